// Round 2
// baseline (225.319 us; speedup 1.0000x reference)
//
#include <hip/hip_runtime.h>

// Q: (2, 5120, 5120) fp32, block-tridiagonal in 1024-blocks.
// Pipeline:
//   decode_kernel  : params -> Ac[i][p][9]   (A-row stencil coeffs, i=b*4+(t-1))
//   offdiag_kernel : Ac -> offd[i][p][9]     (-0.5*(invM+invM^T) entries)
//   diagblk_kernel : Ac -> diag[j][p][25]    (j=b*5+rb; B0^T B0+I+.05 or
//                                             0.5*(M2+M2^T)+I?+.05, 5x5 window)
//   fill_kernel    : pure streaming float4 writes with O(1) table lookup.

#define AC_OFF   0
#define OFFD_OFF 73728           // 8*1024*9
#define DIAG_OFF 147456          // OFFD_OFF + 8*1024*9
// total floats: 147456 + 10*1024*25 = 403456  (~1.6 MB of d_ws)

__device__ __forceinline__ float softplus10(float x) {
  float z = 10.f * x;
  return (fmaxf(z, 0.f) + log1pf(expf(-fabsf(z)))) * 0.1f;
}

__global__ __launch_bounds__(256) void decode_kernel(
    const float* __restrict__ P0, float* __restrict__ Ac) {
  int gid = blockIdx.x * 256 + threadIdx.x;
  if (gid >= 8 * 1024) return;
  int i = gid >> 10;
  int p = gid & 1023;
  int b = i >> 2;
  int t = (i & 3) + 1;
  const float* P = P0 + b * 35 * 1024;

  // kappa/m: reference's raw-reshape axis mixing (q = p*5 + t)
  int qq = p * 5 + t;
  int c  = qq >> 10;
  int r  = qq & 1023;
  float kap = softplus10(P[(0 + c) * 1024 + r]);
  float m1  = P[(5 + c) * 1024 + r];
  float m2  = P[(10 + c) * 1024 + r];

  // gamma/vx/vy: proper transpose layout
  float g  = softplus10(P[(15 + t) * 1024 + p]);
  float vx = P[(20 + t) * 1024 + p];
  float vy = P[(25 + t) * 1024 + p];

  float H11 = g + vx * vx;
  float H22 = g + vy * vy;
  float H12 = vx * vy;

  float co[9];
  co[4] = kap * kap + 2.f * H11 + 2.f * H22;
  co[5] = -H11 + 0.5f * m1;
  co[3] = -H11 - 0.5f * m1;
  co[7] = -H22 + 0.5f * m2;
  co[1] = -H22 - 0.5f * m2;
  co[8] = -0.5f * H12;
  co[0] = -0.5f * H12;
  co[2] =  0.5f * H12;
  co[6] =  0.5f * H12;

  int px = p & 31, py = p >> 5;
  #pragma unroll
  for (int o = 0; o < 9; o++) {
    const int dx = o % 3 - 1, dy = o / 3 - 1;
    int nx = px + dx, ny = py + dy;
    bool valid = (nx >= 0) & (nx < 32) & (ny >= 0) & (ny < 32);
    Ac[(i * 1024 + p) * 9 + o] = (o == 4) ? co[4] : (valid ? co[o] : 0.f);
  }
}

// offd[i][p][o] = -0.5*(invM[p,q] + invM[q,p]),  q = p + dy*32 + dx (0 if q off-grid)
__global__ __launch_bounds__(256) void offdiag_kernel(float* __restrict__ ws) {
  const float* Ac = ws + AC_OFF;
  float* offd = ws + OFFD_OFF;
  int gid = blockIdx.x * 256 + threadIdx.x;
  if (gid >= 8 * 1024) return;
  int i = gid >> 10, p = gid & 1023;
  int px = p & 31, py = p >> 5;
  #pragma unroll
  for (int o = 0; o < 9; o++) {
    const int dx = o % 3 - 1, dy = o / 3 - 1;
    float v = 0.f;
    if (o == 4) {
      v = -(Ac[(i * 1024 + p) * 9 + 4] + 1.f);
    } else {
      int nx = px + dx, ny = py + dy;
      if (nx >= 0 && nx < 32 && ny >= 0 && ny < 32) {
        int q = ny * 32 + nx;
        v = -0.5f * (Ac[(i * 1024 + p) * 9 + o] + Ac[(i * 1024 + q) * 9 + (8 - o)]);
      }
    }
    offd[(i * 1024 + p) * 9 + o] = v;
  }
}

__device__ __forceinline__ float m2e(const float* __restrict__ Ac, int i, int p, int q) {
  int px = p & 31, py = p >> 5, qx = q & 31, qy = q >> 5;
  float s = 0.f;
  #pragma unroll
  for (int o = 0; o < 9; o++) {
    const int dx = o % 3 - 1, dy = o / 3 - 1;
    int kx = px + dx, ky = py + dy;
    if (kx < 0 || kx > 31 || ky < 0 || ky > 31) continue;
    int k = ky * 32 + kx;
    float a = Ac[(i * 1024 + p) * 9 + o] + (o == 4 ? 1.f : 0.f);
    int ddx = qx - kx, ddy = qy - ky;
    if (ddx < -1 || ddx > 1 || ddy < -1 || ddy > 1) continue;
    float bb = Ac[(i * 1024 + k) * 9 + (ddy + 1) * 3 + (ddx + 1)] + (k == q ? 1.f : 0.f);
    s += a * bb;
  }
  return s;
}

__device__ __forceinline__ float btb(const float* __restrict__ Ac, int i0, int p, int q) {
  int px = p & 31, py = p >> 5, qx = q & 31, qy = q >> 5;
  float s = 0.f;
  #pragma unroll
  for (int o = 0; o < 9; o++) {
    const int dx = o % 3 - 1, dy = o / 3 - 1;
    int kx = px + dx, ky = py + dy;
    if (kx < 0 || kx > 31 || ky < 0 || ky > 31) continue;
    int k = ky * 32 + kx;
    float bkp = Ac[(i0 * 1024 + k) * 9 + (8 - o)];
    int ddx = qx - kx, ddy = qy - ky;
    if (ddx < -1 || ddx > 1 || ddy < -1 || ddy > 1) continue;
    float bkq = Ac[(i0 * 1024 + k) * 9 + (ddy + 1) * 3 + (ddx + 1)];
    s += bkp * bkq;
  }
  return s;
}

// diag[j][p][w], j = b*5+rb, w = (dy+2)*5 + (dx+2)
__global__ __launch_bounds__(256) void diagblk_kernel(float* __restrict__ ws) {
  const float* Ac = ws + AC_OFF;
  float* diag = ws + DIAG_OFF;
  int gid = blockIdx.x * 256 + threadIdx.x;
  if (gid >= 10 * 1024) return;
  int j = gid >> 10, p = gid & 1023;
  int b = j / 5, rb = j % 5;
  int px = p & 31, py = p >> 5;
  #pragma unroll
  for (int w = 0; w < 25; w++) {
    const int dx = w % 5 - 2, dy = w / 5 - 2;
    int nx = px + dx, ny = py + dy;
    float v = 0.f;
    if (nx >= 0 && nx < 32 && ny >= 0 && ny < 32) {
      int q = ny * 32 + nx;
      if (rb == 0) {
        v = btb(Ac, b * 4, p, q) + (p == q ? 1.05f : 0.f);
      } else {
        int i = b * 4 + rb - 1;
        float diagAdd = (rb <= 3 ? 1.05f : 0.05f);
        v = 0.5f * (m2e(Ac, i, p, q) + m2e(Ac, i, q, p)) + (p == q ? diagAdd : 0.f);
      }
    }
    diag[(j * 1024 + p) * 25 + w] = v;
  }
}

// grid (5, 5120, 2) x 256; one float4 per thread — pure streaming write.
__global__ __launch_bounds__(256) void fill_kernel(
    const float* __restrict__ ws, float4* __restrict__ out) {
  const int cb  = blockIdx.x;
  const int row = blockIdx.y;
  const int b   = blockIdx.z;
  const int tx  = threadIdx.x;
  const int rb  = row >> 10;
  const int p   = row & 1023;
  const int d   = cb - rb;
  const long oidx = (long)b * 6553600 + (long)row * 1280 + cb * 256 + tx;

  float4 v = make_float4(0.f, 0.f, 0.f, 0.f);
  if (d >= -1 && d <= 1) {
    const int q0  = tx * 4;
    const int qy  = q0 >> 5;
    const int qx0 = q0 & 31;
    const int px  = p & 31, py = p >> 5;
    const int dy  = qy - py;
    float rr[4] = {0.f, 0.f, 0.f, 0.f};
    if (d != 0) {
      if (dy >= -1 && dy <= 1) {
        const int i = b * 4 + (d > 0 ? rb : cb);
        const float* t = ws + OFFD_OFF + ((i * 1024 + p) * 9 + (dy + 1) * 3 + 1) - px;
        #pragma unroll
        for (int jj = 0; jj < 4; jj++) {
          int dx = qx0 + jj - px;
          if (dx >= -1 && dx <= 1) rr[jj] = t[qx0 + jj];
        }
      }
    } else {
      if (dy >= -2 && dy <= 2) {
        const int j = b * 5 + rb;
        const float* t = ws + DIAG_OFF + ((j * 1024 + p) * 25 + (dy + 2) * 5 + 2) - px;
        #pragma unroll
        for (int jj = 0; jj < 4; jj++) {
          int dx = qx0 + jj - px;
          if (dx >= -2 && dx <= 2) rr[jj] = t[qx0 + jj];
        }
      }
    }
    v = make_float4(rr[0], rr[1], rr[2], rr[3]);
  }
  out[oidx] = v;
}

extern "C" void kernel_launch(void* const* d_in, const int* in_sizes, int n_in,
                              void* d_out, int out_size, void* d_ws, size_t ws_size,
                              hipStream_t stream) {
  const float* params = (const float*)d_in[0];  // (2, 35, 32, 32) fp32
  float* ws = (float*)d_ws;                     // ~1.6 MB used
  float4* out = (float4*)d_out;                 // (2, 5120, 5120) fp32

  decode_kernel<<<32, 256, 0, stream>>>(params, ws + AC_OFF);
  offdiag_kernel<<<32, 256, 0, stream>>>(ws);
  diagblk_kernel<<<40, 256, 0, stream>>>(ws);
  dim3 grid(5, 5120, 2);
  fill_kernel<<<grid, 256, 0, stream>>>(ws, out);
}

// Round 3
// 207.922 us; speedup vs baseline: 1.0837x; 1.0837x over previous
//
#include <hip/hip_runtime.h>

// Q: (2, 5120, 5120) fp32, block-tridiagonal in 1024-blocks.
// Pipeline (3 launches):
//   decode_kernel : params -> Ac[i][p][9]  (A-row stencil coeffs, i=b*4+(t-1))
//   tables_kernel : one THREAD per table entry (wide & flat):
//                     offd[i][p][9]  = -0.5*(invM+invM^T) entries
//                     diag[j][p][25] = B0^T B0+I+.05  (rb=0)  or
//                                      0.5*(M2+M2^T)+I?+.05  (rb>=1), j=b*5+rb
//   fill_kernel   : pure streaming float4 writes with O(1) table lookup.

#define AC_OFF   0
#define OFFD_OFF 73728           // 8*1024*9
#define DIAG_OFF 147456          // OFFD_OFF + 8*1024*9
// total ws floats: 147456 + 10*1024*25 = 403456 (~1.6 MB)

__device__ __forceinline__ float softplus10(float x) {
  float z = 10.f * x;
  return (fmaxf(z, 0.f) + log1pf(expf(-fabsf(z)))) * 0.1f;
}

__global__ __launch_bounds__(256) void decode_kernel(
    const float* __restrict__ P0, float* __restrict__ Ac) {
  int gid = blockIdx.x * 256 + threadIdx.x;
  if (gid >= 8 * 1024) return;
  int i = gid >> 10;
  int p = gid & 1023;
  int b = i >> 2;
  int t = (i & 3) + 1;
  const float* P = P0 + b * 35 * 1024;

  // kappa/m: reference's raw-reshape axis mixing (q = p*5 + t)
  int qq = p * 5 + t;
  int c  = qq >> 10;
  int r  = qq & 1023;
  float kap = softplus10(P[(0 + c) * 1024 + r]);
  float m1  = P[(5 + c) * 1024 + r];
  float m2  = P[(10 + c) * 1024 + r];

  // gamma/vx/vy: proper transpose layout
  float g  = softplus10(P[(15 + t) * 1024 + p]);
  float vx = P[(20 + t) * 1024 + p];
  float vy = P[(25 + t) * 1024 + p];

  float H11 = g + vx * vx;
  float H22 = g + vy * vy;
  float H12 = vx * vy;

  float co[9];
  co[4] = kap * kap + 2.f * H11 + 2.f * H22;
  co[5] = -H11 + 0.5f * m1;
  co[3] = -H11 - 0.5f * m1;
  co[7] = -H22 + 0.5f * m2;
  co[1] = -H22 - 0.5f * m2;
  co[8] = -0.5f * H12;
  co[0] = -0.5f * H12;
  co[2] =  0.5f * H12;
  co[6] =  0.5f * H12;

  int px = p & 31, py = p >> 5;
  #pragma unroll
  for (int o = 0; o < 9; o++) {
    const int dx = o % 3 - 1, dy = o / 3 - 1;
    int nx = px + dx, ny = py + dy;
    bool valid = (nx >= 0) & (nx < 32) & (ny >= 0) & (ny < 32);
    Ac[(i * 1024 + p) * 9 + o] = (o == 4) ? co[4] : (valid ? co[o] : 0.f);
  }
}

__device__ __forceinline__ float m2e(const float* __restrict__ Ac, int i, int p, int q) {
  int px = p & 31, py = p >> 5, qx = q & 31, qy = q >> 5;
  float s = 0.f;
  #pragma unroll
  for (int o = 0; o < 9; o++) {
    const int dx = o % 3 - 1, dy = o / 3 - 1;
    int kx = px + dx, ky = py + dy;
    if (kx < 0 || kx > 31 || ky < 0 || ky > 31) continue;
    int k = ky * 32 + kx;
    float a = Ac[(i * 1024 + p) * 9 + o] + (o == 4 ? 1.f : 0.f);
    int ddx = qx - kx, ddy = qy - ky;
    if (ddx < -1 || ddx > 1 || ddy < -1 || ddy > 1) continue;
    float bb = Ac[(i * 1024 + k) * 9 + (ddy + 1) * 3 + (ddx + 1)] + (k == q ? 1.f : 0.f);
    s += a * bb;
  }
  return s;
}

__device__ __forceinline__ float btb(const float* __restrict__ Ac, int i0, int p, int q) {
  int px = p & 31, py = p >> 5, qx = q & 31, qy = q >> 5;
  float s = 0.f;
  #pragma unroll
  for (int o = 0; o < 9; o++) {
    const int dx = o % 3 - 1, dy = o / 3 - 1;
    int kx = px + dx, ky = py + dy;
    if (kx < 0 || kx > 31 || ky < 0 || ky > 31) continue;
    int k = ky * 32 + kx;
    float bkp = Ac[(i0 * 1024 + k) * 9 + (8 - o)];
    int ddx = qx - kx, ddy = qy - ky;
    if (ddx < -1 || ddx > 1 || ddy < -1 || ddy > 1) continue;
    float bkq = Ac[(i0 * 1024 + k) * 9 + (ddy + 1) * 3 + (ddx + 1)];
    s += bkp * bkq;
  }
  return s;
}

// One thread per table entry: [0,73728) -> offd, [73728, 329728) -> diag.
__global__ __launch_bounds__(256) void tables_kernel(float* __restrict__ ws) {
  const float* Ac = ws + AC_OFF;
  int gid = blockIdx.x * 256 + threadIdx.x;
  if (gid < 73728) {
    // offd[i][p][o] = -0.5*(invM[p,q] + invM[q,p])
    int i = gid / 9216;
    int rem = gid - i * 9216;
    int p = rem / 9;
    int o = rem - p * 9;
    int px = p & 31, py = p >> 5;
    int dx = o % 3 - 1, dy = o / 3 - 1;
    float v = 0.f;
    if (o == 4) {
      v = -(Ac[(i * 1024 + p) * 9 + 4] + 1.f);
    } else {
      int nx = px + dx, ny = py + dy;
      if (nx >= 0 && nx < 32 && ny >= 0 && ny < 32) {
        int q = ny * 32 + nx;
        v = -0.5f * (Ac[(i * 1024 + p) * 9 + o] + Ac[(i * 1024 + q) * 9 + (8 - o)]);
      }
    }
    ws[OFFD_OFF + gid] = v;
  } else {
    int e = gid - 73728;
    if (e >= 256000) return;
    // diag[j][p][w], j = b*5+rb, w = (dy+2)*5+(dx+2)
    int j = e / 25600;
    int rem = e - j * 25600;
    int p = rem / 25;
    int w = rem - p * 25;
    int b = j / 5, rb = j - b * 5;
    int px = p & 31, py = p >> 5;
    int dx = w % 5 - 2, dy = w / 5 - 2;
    int nx = px + dx, ny = py + dy;
    float v = 0.f;
    if (nx >= 0 && nx < 32 && ny >= 0 && ny < 32) {
      int q = ny * 32 + nx;
      if (rb == 0) {
        v = btb(Ac, b * 4, p, q) + (p == q ? 1.05f : 0.f);
      } else {
        int i = b * 4 + rb - 1;
        float diagAdd = (rb <= 3 ? 1.05f : 0.05f);
        v = 0.5f * (m2e(Ac, i, p, q) + m2e(Ac, i, q, p)) + (p == q ? diagAdd : 0.f);
      }
    }
    ws[DIAG_OFF + e] = v;
  }
}

// grid (5, 5120, 2) x 256; one float4 per thread — pure streaming write.
__global__ __launch_bounds__(256) void fill_kernel(
    const float* __restrict__ ws, float4* __restrict__ out) {
  const int cb  = blockIdx.x;
  const int row = blockIdx.y;
  const int b   = blockIdx.z;
  const int tx  = threadIdx.x;
  const int rb  = row >> 10;
  const int p   = row & 1023;
  const int d   = cb - rb;
  const long oidx = (long)b * 6553600 + (long)row * 1280 + cb * 256 + tx;

  float4 v = make_float4(0.f, 0.f, 0.f, 0.f);
  if (d >= -1 && d <= 1) {
    const int q0  = tx * 4;
    const int qy  = q0 >> 5;
    const int qx0 = q0 & 31;
    const int px  = p & 31, py = p >> 5;
    const int dy  = qy - py;
    float rr[4] = {0.f, 0.f, 0.f, 0.f};
    if (d != 0) {
      if (dy >= -1 && dy <= 1) {
        const int i = b * 4 + (d > 0 ? rb : cb);
        const float* t = ws + OFFD_OFF + ((i * 1024 + p) * 9 + (dy + 1) * 3 + 1) - px;
        #pragma unroll
        for (int jj = 0; jj < 4; jj++) {
          int dx = qx0 + jj - px;
          if (dx >= -1 && dx <= 1) rr[jj] = t[qx0 + jj];
        }
      }
    } else {
      if (dy >= -2 && dy <= 2) {
        const int j = b * 5 + rb;
        const float* t = ws + DIAG_OFF + ((j * 1024 + p) * 25 + (dy + 2) * 5 + 2) - px;
        #pragma unroll
        for (int jj = 0; jj < 4; jj++) {
          int dx = qx0 + jj - px;
          if (dx >= -2 && dx <= 2) rr[jj] = t[qx0 + jj];
        }
      }
    }
    v = make_float4(rr[0], rr[1], rr[2], rr[3]);
  }
  out[oidx] = v;
}

extern "C" void kernel_launch(void* const* d_in, const int* in_sizes, int n_in,
                              void* d_out, int out_size, void* d_ws, size_t ws_size,
                              hipStream_t stream) {
  const float* params = (const float*)d_in[0];  // (2, 35, 32, 32) fp32
  float* ws = (float*)d_ws;                     // ~1.6 MB used
  float4* out = (float4*)d_out;                 // (2, 5120, 5120) fp32

  decode_kernel<<<32, 256, 0, stream>>>(params, ws + AC_OFF);
  tables_kernel<<<1288, 256, 0, stream>>>(ws);  // 329728 entry-threads
  dim3 grid(5, 5120, 2);
  fill_kernel<<<grid, 256, 0, stream>>>(ws, out);
}